// Round 1
// 504.393 us; speedup vs baseline: 1.3337x; 1.3337x over previous
//
#include <hip/hip_runtime.h>

#define B_    4
#define N_    50000
#define E_    800000
#define FIN_  128
#define F_    64
#define BN_   (B_ * N_)        // 200000
#define TOT_  (BN_ * F_)       // 12,800,000
#define BE_   (B_ * E_)        // 3,200,000
#define ALPHA_ 0.2f
#define NEG_BIG_ -9.0e15f

#define XS_STRIDE 132
#define GEMM_BLOCKS (BN_ / 64)     // 3125
#define COUNT_BLOCKS (BE_ / 1024)  // 3125 (4 edges/thread)

__device__ __forceinline__ float bf2f(unsigned int u16) {
    union { unsigned int i; float f; } v;
    v.i = u16 << 16;
    return v.f;
}
__device__ __forceinline__ unsigned int f2bf(float f) {
    union { float f; unsigned int u; } v;
    v.f = f;
    unsigned int r = v.u + 0x7FFFu + ((v.u >> 16) & 1u);  // RNE
    return r >> 16;
}

// ---- Kernel 1: fused [gemm | count+rank], roles interleaved by bid&1 ------
// gemm role:  h = X@W (bf16 packed -> hq), e1/e2 (fp32)
// count role: cnt[gs]++ via atomicAdd; old value stored as rank[edge]
__global__ __launch_bounds__(256) void gemm_count_kernel(
    const float* __restrict__ X,
    const float* __restrict__ W,
    const float* __restrict__ a,
    const int* __restrict__ edges,
    unsigned short* __restrict__ hq,
    float* __restrict__ e1,
    float* __restrict__ e2,
    int* __restrict__ cnt,
    unsigned short* __restrict__ rank) {
    __shared__ float Wf[FIN_ * F_];            // 32 KB
    __shared__ float Xs[64 * XS_STRIDE];       // 33.8 KB

    const int tid = threadIdx.x;
    const int bid = blockIdx.x;

    if (bid & 1) {
        // ---------------- count role: 4 edges per thread ----------------
        const int g  = (bid >> 1) * 256 + tid;     // 0 .. BE_/4
        const int ge = g * 4;
        const int b  = ge / E_;
        const int e  = ge - b * E_;
        const int4 s4 = *(const int4*)&edges[(size_t)b * 2 * E_ + e];
        ushort4 r4;
        r4.x = (unsigned short)atomicAdd(&cnt[b * N_ + s4.x], 1);
        r4.y = (unsigned short)atomicAdd(&cnt[b * N_ + s4.y], 1);
        r4.z = (unsigned short)atomicAdd(&cnt[b * N_ + s4.z], 1);
        r4.w = (unsigned short)atomicAdd(&cnt[b * N_ + s4.w], 1);
        *(ushort4*)&rank[ge] = r4;
        return;
    }

    // ---------------- gemm role ----------------
    const float4* Wg = (const float4*)W;
    for (int i = tid; i < 2048; i += 256)
        ((float4*)Wf)[i] = Wg[i];

    const int row0 = (bid >> 1) * 64;
    const float4* Xg = (const float4*)(X + (size_t)row0 * FIN_);
    for (int i = tid; i < 2048; i += 256) {
        const int r = i >> 5;
        const int c = i & 31;
        float4 v = Xg[i];
        *(float4*)&Xs[r * XS_STRIDE + c * 4] = v;
    }
    __syncthreads();

    const int cg = tid & 15;
    const int rg = tid >> 4;

    float acc[4][4] = {};
#pragma unroll 4
    for (int k = 0; k < FIN_; ++k) {
        const float4 wv = *(const float4*)&Wf[k * F_ + cg * 4];
        float xr[4];
#pragma unroll
        for (int j = 0; j < 4; ++j)
            xr[j] = Xs[(rg * 4 + j) * XS_STRIDE + k];
#pragma unroll
        for (int j = 0; j < 4; ++j) {
            acc[j][0] += xr[j] * wv.x;
            acc[j][1] += xr[j] * wv.y;
            acc[j][2] += xr[j] * wv.z;
            acc[j][3] += xr[j] * wv.w;
        }
    }

    float a1v[4], a2v[4];
#pragma unroll
    for (int i = 0; i < 4; ++i) {
        a1v[i] = a[cg * 4 + i];
        a2v[i] = a[F_ + cg * 4 + i];
    }

#pragma unroll
    for (int j = 0; j < 4; ++j) {
        const int row = row0 + rg * 4 + j;
        union { ushort4 v; unsigned short s[4]; } st;
#pragma unroll
        for (int i = 0; i < 4; ++i) st.s[i] = (unsigned short)f2bf(acc[j][i]);
        *(ushort4*)&hq[(size_t)row * F_ + cg * 4] = st.v;   // 8B-aligned

        float p1 = acc[j][0] * a1v[0] + acc[j][1] * a1v[1] +
                   acc[j][2] * a1v[2] + acc[j][3] * a1v[3];
        float p2 = acc[j][0] * a2v[0] + acc[j][1] * a2v[1] +
                   acc[j][2] * a2v[2] + acc[j][3] * a2v[3];
#pragma unroll
        for (int m = 8; m >= 1; m >>= 1) {
            p1 += __shfl_xor(p1, m);
            p2 += __shfl_xor(p2, m);
        }
        if (cg == 0) { e1[row] = p1; e2[row] = p2; }
    }
}

// ---- 3-phase multi-block exclusive scan: cnt[BN] -> offs[BN+1] -----------
#define SB_ 196
#define SE_ 1024

__global__ __launch_bounds__(256) void scanA_kernel(
    const int* __restrict__ cnt, int* __restrict__ bsum) {
    __shared__ int red[256];
    const int t = threadIdx.x;
    const int base = blockIdx.x * SE_ + t * 4;
    int s = 0;
    if (base < BN_) {
        const int4 v = *(const int4*)&cnt[base];
        s = v.x + v.y + v.z + v.w;
    }
    red[t] = s;
    __syncthreads();
    for (int off = 128; off >= 1; off >>= 1) {
        if (t < off) red[t] += red[t + off];
        __syncthreads();
    }
    if (t == 0) bsum[blockIdx.x] = red[0];
}

__global__ __launch_bounds__(256) void scanB_kernel(
    const int* __restrict__ bsum, int* __restrict__ boff,
    int* __restrict__ offs) {
    __shared__ int s[256];
    const int t = threadIdx.x;
    const int v = (t < SB_) ? bsum[t] : 0;
    s[t] = v;
    __syncthreads();
    for (int off = 1; off < 256; off <<= 1) {
        const int u = (t >= off) ? s[t - off] : 0;
        __syncthreads();
        s[t] += u;
        __syncthreads();
    }
    if (t < SB_) boff[t] = s[t] - v;
    if (t == SB_ - 1) offs[BN_] = s[t];
}

__global__ __launch_bounds__(256) void scanC_kernel(
    const int* __restrict__ cnt, const int* __restrict__ boff,
    int* __restrict__ offs) {
    __shared__ int s[256];
    const int t = threadIdx.x;
    const int base = blockIdx.x * SE_ + t * 4;
    int4 v = make_int4(0, 0, 0, 0);
    if (base < BN_) v = *(const int4*)&cnt[base];
    const int tot = v.x + v.y + v.z + v.w;
    s[t] = tot;
    __syncthreads();
    for (int off = 1; off < 256; off <<= 1) {
        const int u = (t >= off) ? s[t - off] : 0;
        __syncthreads();
        s[t] += u;
        __syncthreads();
    }
    if (base < BN_) {
        int run = boff[blockIdx.x] + s[t] - tot;
        int4 o;
        o.x = run;
        o.y = run + v.x;
        o.z = o.y + v.y;
        o.w = o.z + v.z;
        *(int4*)&offs[base] = o;
    }
}

// ---- Kernel 4: place (dst16 | wt_bf16) into CSR slots, ALL batches, -------
//      atomic-free via precomputed rank. 4 edges/thread.
__global__ __launch_bounds__(256) void place_kernel(
    const int* __restrict__ edges,
    const float* __restrict__ e1,
    const float* __restrict__ e2,
    const int* __restrict__ offs,
    const unsigned short* __restrict__ rank,
    unsigned int* __restrict__ csr) {
    const int g  = blockIdx.x * 256 + threadIdx.x;   // grid exact: BE_/1024
    const int ge = g * 4;
    const int b  = ge / E_;
    const int e  = ge - b * E_;
    const int4 s4 = *(const int4*)&edges[(size_t)b * 2 * E_ + e];
    const int4 d4 = *(const int4*)&edges[(size_t)b * 2 * E_ + E_ + e];
    const ushort4 r4 = *(const ushort4*)&rank[ge];
    const int ss[4] = { s4.x, s4.y, s4.z, s4.w };
    const int dd[4] = { d4.x, d4.y, d4.z, d4.w };
    const int rr[4] = { r4.x, r4.y, r4.z, r4.w };
#pragma unroll
    for (int j = 0; j < 4; ++j) {
        const int gs = b * N_ + ss[j];
        const float sv = e1[gs] + e2[b * N_ + dd[j]];
        const float lr = sv > 0.0f ? sv : ALPHA_ * sv;
        const float wt = __expf(-lr);
        csr[offs[gs] + rr[j]] = (unsigned int)dd[j] | (f2bf(wt) << 16);
    }
}

// ---- Kernel 5: gather + normalize + elu, ALL batches. Wave per node. -----
__global__ __launch_bounds__(256) void gather_kernel(
    const int* __restrict__ offs,
    const unsigned int* __restrict__ csr,
    const unsigned int* __restrict__ hq_u,  // packed bf16 pairs, [BN][32]
    float* __restrict__ out) {
    const int lane = threadIdx.x & 63;
    const int half = lane >> 5;
    const int sub = lane & 31;
    const int gs = (int)((blockIdx.x * 256 + threadIdx.x) >> 6);  // 0..BN_
    const int b = gs / N_;
    const unsigned int* hbu = hq_u + (size_t)b * N_ * 32;
    const int k0 = offs[gs];
    const int k1 = offs[gs + 1];
    float a0 = 0.0f, a1 = 0.0f, rs = 0.0f;
    for (int k = k0 + half; k < k1; k += 2) {
        const unsigned int ent = csr[k];
        const int d = (int)(ent & 0xFFFFu);
        const float wt = bf2f(ent >> 16);
        const unsigned int pk = hbu[(size_t)d * 32 + sub];
        a0 += wt * bf2f(pk & 0xFFFFu);
        a1 += wt * bf2f(pk >> 16);
        rs += wt;
    }
    a0 += __shfl_xor(a0, 32);
    a1 += __shfl_xor(a1, 32);
    rs += __shfl_xor(rs, 32);
    if (half == 0) {
        float v0 = a0 / rs, v1 = a1 / rs;
        if (v0 != v0) v0 = NEG_BIG_;
        if (v1 != v1) v1 = NEG_BIG_;
        v0 = v0 > 0.0f ? v0 : (__expf(v0) - 1.0f);
        v1 = v1 > 0.0f ? v1 : (__expf(v1) - 1.0f);
        *(float2*)&out[(size_t)gs * F_ + sub * 2] = make_float2(v0, v1);
    }
}

extern "C" void kernel_launch(void* const* d_in, const int* in_sizes, int n_in,
                              void* d_out, int out_size, void* d_ws, size_t ws_size,
                              hipStream_t stream) {
    const float* X = (const float*)d_in[0];
    const int* edges = (const int*)d_in[1];
    const float* W = (const float*)d_in[2];
    const float* a = (const float*)d_in[3];
    float* out = (float*)d_out;

    // ws layout (~48.0 MB, proven >= 53.6 MB available):
    // [e1 BN f32][e2 BN f32][hq BN*64 bf16][cnt BN i32][offs BN+4 i32]
    // [rank BE u16][csr BE u32][bsum 256][boff 256]
    float* e1 = (float*)d_ws;
    float* e2 = e1 + BN_;
    unsigned short* hq = (unsigned short*)(e2 + BN_);
    int* cnt = (int*)(hq + (size_t)BN_ * F_);
    int* offs = cnt + BN_;
    unsigned short* rank = (unsigned short*)(offs + BN_ + 4);
    unsigned int* csr = (unsigned int*)(rank + BE_);
    int* bsum = (int*)(csr + BE_);
    int* boff = bsum + 256;

    hipMemsetAsync(cnt, 0, (size_t)BN_ * sizeof(int), stream);

    gemm_count_kernel<<<GEMM_BLOCKS + COUNT_BLOCKS, 256, 0, stream>>>(
        X, W, a, edges, hq, e1, e2, cnt, rank);
    scanA_kernel<<<SB_, 256, 0, stream>>>(cnt, bsum);
    scanB_kernel<<<1, 256, 0, stream>>>(bsum, boff, offs);
    scanC_kernel<<<SB_, 256, 0, stream>>>(cnt, boff, offs);
    place_kernel<<<BE_ / 1024, 256, 0, stream>>>(edges, e1, e2, offs, rank, csr);
    gather_kernel<<<(TOT_ / 64) / 4, 256, 0, stream>>>(offs, csr, (const unsigned int*)hq, out);
}

// Round 2
// 435.214 us; speedup vs baseline: 1.5457x; 1.1590x over previous
//
#include <hip/hip_runtime.h>

#define B_    4
#define N_    50000
#define E_    800000
#define FIN_  128
#define F_    64
#define BN_   (B_ * N_)        // 200000
#define TOT_  (BN_ * F_)       // 12,800,000
#define BE_   (B_ * E_)        // 3,200,000
#define ALPHA_ 0.2f
#define NEG_BIG_ -9.0e15f

#define XS_STRIDE 132
#define GEMM_BLOCKS (BN_ / 64)     // 3125
#define COUNT_BLOCKS (BE_ / 1024)  // 3125 (4 edges/thread)

__device__ __forceinline__ float bf2f(unsigned int u16) {
    union { unsigned int i; float f; } v;
    v.i = u16 << 16;
    return v.f;
}
__device__ __forceinline__ unsigned int f2bf(float f) {
    union { float f; unsigned int u; } v;
    v.f = f;
    unsigned int r = v.u + 0x7FFFu + ((v.u >> 16) & 1u);  // RNE
    return r >> 16;
}

// ---- Kernel 1: fused [gemm | count+rank], roles interleaved by bid&1 ------
// gemm role:  h = X@W (bf16 packed -> hq), e1/e2 (fp32)
// count role: cnt[gs]++ via atomicAdd; old value stored as rank[edge]
__global__ __launch_bounds__(256) void gemm_count_kernel(
    const float* __restrict__ X,
    const float* __restrict__ W,
    const float* __restrict__ a,
    const int* __restrict__ edges,
    unsigned short* __restrict__ hq,
    float* __restrict__ e1,
    float* __restrict__ e2,
    int* __restrict__ cnt,
    unsigned short* __restrict__ rank) {
    __shared__ float Wf[FIN_ * F_];            // 32 KB
    __shared__ float Xs[64 * XS_STRIDE];       // 33.8 KB

    const int tid = threadIdx.x;
    const int bid = blockIdx.x;

    if (bid & 1) {
        // ---------------- count role: 4 edges per thread ----------------
        const int g  = (bid >> 1) * 256 + tid;     // 0 .. BE_/4
        const int ge = g * 4;
        const int b  = ge / E_;
        const int e  = ge - b * E_;
        const int4 s4 = *(const int4*)&edges[(size_t)b * 2 * E_ + e];
        ushort4 r4;
        r4.x = (unsigned short)atomicAdd(&cnt[b * N_ + s4.x], 1);
        r4.y = (unsigned short)atomicAdd(&cnt[b * N_ + s4.y], 1);
        r4.z = (unsigned short)atomicAdd(&cnt[b * N_ + s4.z], 1);
        r4.w = (unsigned short)atomicAdd(&cnt[b * N_ + s4.w], 1);
        *(ushort4*)&rank[ge] = r4;
        return;
    }

    // ---------------- gemm role ----------------
    const float4* Wg = (const float4*)W;
    for (int i = tid; i < 2048; i += 256)
        ((float4*)Wf)[i] = Wg[i];

    const int row0 = (bid >> 1) * 64;
    const float4* Xg = (const float4*)(X + (size_t)row0 * FIN_);
    for (int i = tid; i < 2048; i += 256) {
        const int r = i >> 5;
        const int c = i & 31;
        float4 v = Xg[i];
        *(float4*)&Xs[r * XS_STRIDE + c * 4] = v;
    }
    __syncthreads();

    const int cg = tid & 15;
    const int rg = tid >> 4;

    float acc[4][4] = {};
#pragma unroll 4
    for (int k = 0; k < FIN_; ++k) {
        const float4 wv = *(const float4*)&Wf[k * F_ + cg * 4];
        float xr[4];
#pragma unroll
        for (int j = 0; j < 4; ++j)
            xr[j] = Xs[(rg * 4 + j) * XS_STRIDE + k];
#pragma unroll
        for (int j = 0; j < 4; ++j) {
            acc[j][0] += xr[j] * wv.x;
            acc[j][1] += xr[j] * wv.y;
            acc[j][2] += xr[j] * wv.z;
            acc[j][3] += xr[j] * wv.w;
        }
    }

    float a1v[4], a2v[4];
#pragma unroll
    for (int i = 0; i < 4; ++i) {
        a1v[i] = a[cg * 4 + i];
        a2v[i] = a[F_ + cg * 4 + i];
    }

#pragma unroll
    for (int j = 0; j < 4; ++j) {
        const int row = row0 + rg * 4 + j;
        union { ushort4 v; unsigned short s[4]; } st;
#pragma unroll
        for (int i = 0; i < 4; ++i) st.s[i] = (unsigned short)f2bf(acc[j][i]);
        *(ushort4*)&hq[(size_t)row * F_ + cg * 4] = st.v;   // 8B-aligned

        float p1 = acc[j][0] * a1v[0] + acc[j][1] * a1v[1] +
                   acc[j][2] * a1v[2] + acc[j][3] * a1v[3];
        float p2 = acc[j][0] * a2v[0] + acc[j][1] * a2v[1] +
                   acc[j][2] * a2v[2] + acc[j][3] * a2v[3];
#pragma unroll
        for (int m = 8; m >= 1; m >>= 1) {
            p1 += __shfl_xor(p1, m);
            p2 += __shfl_xor(p2, m);
        }
        if (cg == 0) { e1[row] = p1; e2[row] = p2; }
    }
}

// ---- 3-phase multi-block exclusive scan: cnt[BN] -> offs[BN+1] -----------
#define SB_ 196
#define SE_ 1024

__global__ __launch_bounds__(256) void scanA_kernel(
    const int* __restrict__ cnt, int* __restrict__ bsum) {
    __shared__ int red[256];
    const int t = threadIdx.x;
    const int base = blockIdx.x * SE_ + t * 4;
    int s = 0;
    if (base < BN_) {
        const int4 v = *(const int4*)&cnt[base];
        s = v.x + v.y + v.z + v.w;
    }
    red[t] = s;
    __syncthreads();
    for (int off = 128; off >= 1; off >>= 1) {
        if (t < off) red[t] += red[t + off];
        __syncthreads();
    }
    if (t == 0) bsum[blockIdx.x] = red[0];
}

__global__ __launch_bounds__(256) void scanB_kernel(
    const int* __restrict__ bsum, int* __restrict__ boff,
    int* __restrict__ offs) {
    __shared__ int s[256];
    const int t = threadIdx.x;
    const int v = (t < SB_) ? bsum[t] : 0;
    s[t] = v;
    __syncthreads();
    for (int off = 1; off < 256; off <<= 1) {
        const int u = (t >= off) ? s[t - off] : 0;
        __syncthreads();
        s[t] += u;
        __syncthreads();
    }
    if (t < SB_) boff[t] = s[t] - v;
    if (t == SB_ - 1) offs[BN_] = s[t];
}

__global__ __launch_bounds__(256) void scanC_kernel(
    const int* __restrict__ cnt, const int* __restrict__ boff,
    int* __restrict__ offs) {
    __shared__ int s[256];
    const int t = threadIdx.x;
    const int base = blockIdx.x * SE_ + t * 4;
    int4 v = make_int4(0, 0, 0, 0);
    if (base < BN_) v = *(const int4*)&cnt[base];
    const int tot = v.x + v.y + v.z + v.w;
    s[t] = tot;
    __syncthreads();
    for (int off = 1; off < 256; off <<= 1) {
        const int u = (t >= off) ? s[t - off] : 0;
        __syncthreads();
        s[t] += u;
        __syncthreads();
    }
    if (base < BN_) {
        int run = boff[blockIdx.x] + s[t] - tot;
        int4 o;
        o.x = run;
        o.y = run + v.x;
        o.z = o.y + v.y;
        o.w = o.z + v.z;
        *(int4*)&offs[base] = o;
    }
}

// ---- Kernel 4: place (dst16 | wt_bf16) into CSR slots, ALL batches, -------
//      atomic-free via precomputed rank. 4 edges/thread.
__global__ __launch_bounds__(256) void place_kernel(
    const int* __restrict__ edges,
    const float* __restrict__ e1,
    const float* __restrict__ e2,
    const int* __restrict__ offs,
    const unsigned short* __restrict__ rank,
    unsigned int* __restrict__ csr) {
    const int g  = blockIdx.x * 256 + threadIdx.x;   // grid exact: BE_/1024
    const int ge = g * 4;
    const int b  = ge / E_;
    const int e  = ge - b * E_;
    const int4 s4 = *(const int4*)&edges[(size_t)b * 2 * E_ + e];
    const int4 d4 = *(const int4*)&edges[(size_t)b * 2 * E_ + E_ + e];
    const ushort4 r4 = *(const ushort4*)&rank[ge];
    const int ss[4] = { s4.x, s4.y, s4.z, s4.w };
    const int dd[4] = { d4.x, d4.y, d4.z, d4.w };
    const int rr[4] = { r4.x, r4.y, r4.z, r4.w };
#pragma unroll
    for (int j = 0; j < 4; ++j) {
        const int gs = b * N_ + ss[j];
        const float sv = e1[gs] + e2[b * N_ + dd[j]];
        const float lr = sv > 0.0f ? sv : ALPHA_ * sv;
        const float wt = __expf(-lr);
        csr[offs[gs] + rr[j]] = (unsigned int)dd[j] | (f2bf(wt) << 16);
    }
}

// ---- Kernel 5: gather + normalize + elu, ALL batches. Wave per node. -----
// 4 edge-groups x 16 lanes, uint2 (8B) per lane, csr prefetched 2 deep so
// the h-row gather for edge i+1 issues before edge i is consumed.
__global__ __launch_bounds__(256) void gather_kernel(
    const int* __restrict__ offs,
    const unsigned int* __restrict__ csr,
    const uint2* __restrict__ hq2,   // packed bf16 quads, [BN][16]
    float* __restrict__ out) {
    const int lane = threadIdx.x & 63;
    const int grp = lane >> 4;       // 0..3 edge group
    const int sub = lane & 15;       // 0..15 feature quad
    const int gs = (int)((blockIdx.x * 256 + threadIdx.x) >> 6);  // 0..BN_
    const int b = gs / N_;
    const uint2* hb = hq2 + (size_t)b * N_ * 16;
    const int k0 = offs[gs];
    const int k1 = offs[gs + 1];

    float a0 = 0.0f, a1 = 0.0f, a2 = 0.0f, a3 = 0.0f, rs = 0.0f;

    int k = k0 + grp;
    unsigned int e_cur = 0u, e_nxt = 0u;
    uint2 p_cur = make_uint2(0u, 0u);
    if (k < k1) e_cur = csr[k];
    if (k + 4 < k1) e_nxt = csr[k + 4];
    if (k < k1) p_cur = hb[(size_t)(e_cur & 0xFFFFu) * 16 + sub];

    for (; k < k1; k += 4) {
        uint2 p_nxt = make_uint2(0u, 0u);
        if (k + 4 < k1) p_nxt = hb[(size_t)(e_nxt & 0xFFFFu) * 16 + sub];
        unsigned int e_nn = 0u;
        if (k + 8 < k1) e_nn = csr[k + 8];

        const float wt = bf2f(e_cur >> 16);
        a0 += wt * bf2f(p_cur.x & 0xFFFFu);
        a1 += wt * bf2f(p_cur.x >> 16);
        a2 += wt * bf2f(p_cur.y & 0xFFFFu);
        a3 += wt * bf2f(p_cur.y >> 16);
        rs += wt;

        e_cur = e_nxt; e_nxt = e_nn; p_cur = p_nxt;
    }

    // reduce across the 4 edge groups
    a0 += __shfl_xor(a0, 16); a1 += __shfl_xor(a1, 16);
    a2 += __shfl_xor(a2, 16); a3 += __shfl_xor(a3, 16);
    rs += __shfl_xor(rs, 16);
    a0 += __shfl_xor(a0, 32); a1 += __shfl_xor(a1, 32);
    a2 += __shfl_xor(a2, 32); a3 += __shfl_xor(a3, 32);
    rs += __shfl_xor(rs, 32);

    if (grp == 0) {
        float v[4];
        v[0] = a0 / rs; v[1] = a1 / rs; v[2] = a2 / rs; v[3] = a3 / rs;
        float4 o;
        float* po = (float*)&o;
#pragma unroll
        for (int j = 0; j < 4; ++j) {
            float x = v[j];
            if (x != x) x = NEG_BIG_;
            po[j] = x > 0.0f ? x : (__expf(x) - 1.0f);
        }
        *(float4*)&out[(size_t)gs * F_ + sub * 4] = o;
    }
}

extern "C" void kernel_launch(void* const* d_in, const int* in_sizes, int n_in,
                              void* d_out, int out_size, void* d_ws, size_t ws_size,
                              hipStream_t stream) {
    const float* X = (const float*)d_in[0];
    const int* edges = (const int*)d_in[1];
    const float* W = (const float*)d_in[2];
    const float* a = (const float*)d_in[3];
    float* out = (float*)d_out;

    // ws layout (~48.0 MB, proven >= 53.6 MB available):
    // [e1 BN f32][e2 BN f32][hq BN*64 bf16][cnt BN i32][offs BN+4 i32]
    // [rank BE u16][csr BE u32][bsum 256][boff 256]
    float* e1 = (float*)d_ws;
    float* e2 = e1 + BN_;
    unsigned short* hq = (unsigned short*)(e2 + BN_);
    int* cnt = (int*)(hq + (size_t)BN_ * F_);
    int* offs = cnt + BN_;
    unsigned short* rank = (unsigned short*)(offs + BN_ + 4);
    unsigned int* csr = (unsigned int*)(rank + BE_);
    int* bsum = (int*)(csr + BE_);
    int* boff = bsum + 256;

    hipMemsetAsync(cnt, 0, (size_t)BN_ * sizeof(int), stream);

    gemm_count_kernel<<<GEMM_BLOCKS + COUNT_BLOCKS, 256, 0, stream>>>(
        X, W, a, edges, hq, e1, e2, cnt, rank);
    scanA_kernel<<<SB_, 256, 0, stream>>>(cnt, bsum);
    scanB_kernel<<<1, 256, 0, stream>>>(bsum, boff, offs);
    scanC_kernel<<<SB_, 256, 0, stream>>>(cnt, boff, offs);
    place_kernel<<<BE_ / 1024, 256, 0, stream>>>(edges, e1, e2, offs, rank, csr);
    gather_kernel<<<BN_ / 4, 256, 0, stream>>>(offs, csr, (const uint2*)hq, out);
}